// Round 2
// baseline (423.017 us; speedup 1.0000x reference)
//
#include <hip/hip_runtime.h>
#include <hip/hip_bf16.h>
#include <math.h>

#define DM   1024
#define HD   1024
#define NH   16
#define DK   64
#define SEQ  2048
#define BATCH 2

typedef __attribute__((ext_vector_type(8))) short bf16x8;
typedef __attribute__((ext_vector_type(4))) float f32x4;

static __device__ __forceinline__ short f2b(float f) {
  union { float f; unsigned u; } v; v.f = f;
  unsigned r = (v.u + 0x7fffu + ((v.u >> 16) & 1u)) >> 16;
  return (short)r;
}

static __device__ __forceinline__ void gload_lds16(const void* g, void* l) {
  __builtin_amdgcn_global_load_lds(
      (const __attribute__((address_space(1))) void*)g,
      (__attribute__((address_space(3))) void*)l, 16, 0, 0);
}

// ---------------- prep kernels ----------------

__global__ __launch_bounds__(256) void k_cvt_h(const float* __restrict__ in,
                                               short* __restrict__ out) {
  int i = (blockIdx.x * 256 + threadIdx.x) * 8;
  float4 a = *reinterpret_cast<const float4*>(in + i);
  float4 b = *reinterpret_cast<const float4*>(in + i + 4);
  bf16x8 o;
  o[0] = f2b(a.x); o[1] = f2b(a.y); o[2] = f2b(a.z); o[3] = f2b(a.w);
  o[4] = f2b(b.x); o[5] = f2b(b.y); o[6] = f2b(b.z); o[7] = f2b(b.w);
  *reinterpret_cast<bf16x8*>(out + i) = o;
}

// transpose + convert 1024x1024 fp32 [K][N] -> bf16 [N][K]; z selects matrix
__global__ __launch_bounds__(256) void k_wtrans(const float* __restrict__ Wq,
                                                const float* __restrict__ Wk,
                                                const float* __restrict__ Wv,
                                                const float* __restrict__ Wo,
                                                short* __restrict__ Wts) {
  const float* src = (blockIdx.z == 0) ? Wq : (blockIdx.z == 1) ? Wk
                   : (blockIdx.z == 2) ? Wv : Wo;
  short* dst = Wts + (size_t)blockIdx.z * DM * HD;
  __shared__ float t[32][33];
  int tx = threadIdx.x & 31, ty = threadIdx.x >> 5;  // ty 0..7
  int k0 = blockIdx.y * 32, n0 = blockIdx.x * 32;
#pragma unroll
  for (int i = 0; i < 4; ++i)
    t[ty + i * 8][tx] = src[(size_t)(k0 + ty + i * 8) * 1024 + n0 + tx];
  __syncthreads();
#pragma unroll
  for (int i = 0; i < 4; ++i)
    dst[(size_t)(n0 + ty + i * 8) * 1024 + k0 + tx] = f2b(t[tx][ty + i * 8]);
}

// bias table: btab[h][pos], pos = delta + 2047, delta = kv - q
__global__ __launch_bounds__(256) void k_bias(const float* __restrict__ rel_bias,
                                              float* __restrict__ btab) {
  int idx = blockIdx.x * 256 + threadIdx.x;  // 65536
  int h = idx >> 12, pos = idx & 4095;
  int delta = pos - 2047;
  int rb = (delta > 0) ? 16 : 0;
  int ar = (delta < 0) ? -delta : delta;
  int bb;
  if (ar < 8) bb = ar;
  else {
    bb = 8 + (int)(logf((float)ar * 0.125f) * (8.0f / 2.7725887222397811f));
    if (bb > 15) bb = 15;
  }
  btab[idx] = rel_bias[(rb + bb) * NH + h];
}

// V [4096][1024] bf16 -> Vt[bh][dk=64][seq=2048] bf16
__global__ __launch_bounds__(256) void k_vtrans(const short* __restrict__ Vb,
                                                short* __restrict__ Vt) {
  int bh = blockIdx.y, b = bh >> 4, h = bh & 15;
  int st = blockIdx.x * 64;
  __shared__ short t[64][72];
  int tx = threadIdx.x & 15, ty = threadIdx.x >> 4;
#pragma unroll
  for (int i = 0; i < 4; ++i) {
    int row = ty + i * 16;
    *reinterpret_cast<short4*>(&t[row][tx * 4]) =
        *reinterpret_cast<const short4*>(
            &Vb[(size_t)(b * SEQ + st + row) * HD + h * 64 + tx * 4]);
  }
  __syncthreads();
#pragma unroll
  for (int i = 0; i < 4; ++i) {
    int dk = ty + i * 16;
    short4 v = make_short4(t[tx * 4 + 0][dk], t[tx * 4 + 1][dk],
                           t[tx * 4 + 2][dk], t[tx * 4 + 3][dk]);
    *reinterpret_cast<short4*>(
        &Vt[(size_t)bh * DK * SEQ + (size_t)dk * SEQ + st + tx * 4]) = v;
  }
}

// ---------------- GEMM: C[M][1024] = A[M][1024]bf16 * Bt[1024][1024]bf16^T ----
// 128x128 tile, 4 waves (2x2), K-step 32, global_load_lds staging (m97 form)
template <int OUTF32>
__global__ __launch_bounds__(256) void k_gemm_bt(const short* __restrict__ A,
                                                 const short* __restrict__ Bt,
                                                 void* __restrict__ Cv,
                                                 size_t btz, size_t cz) {
  __shared__ __align__(16) short As[128 * 32];
  __shared__ __align__(16) short Bs[128 * 32];
  const int tid = threadIdx.x, w = tid >> 6, lane = tid & 63;
  const int wr = w >> 1, wc = w & 1, lg = lane >> 4, l15 = lane & 15;
  const int rowBase = blockIdx.y * 128, colBase = blockIdx.x * 128;
  const short* B = Bt + (size_t)blockIdx.z * btz;

  f32x4 acc[4][4];
#pragma unroll
  for (int m = 0; m < 4; ++m)
#pragma unroll
    for (int n = 0; n < 4; ++n) acc[m][n] = (f32x4){0.f, 0.f, 0.f, 0.f};

  const int c1 = w * 64 + lane, c2 = c1 + 256;
  const short* Ap1 = A + (size_t)(rowBase + (c1 >> 2)) * 1024 + (c1 & 3) * 8;
  const short* Ap2 = A + (size_t)(rowBase + (c2 >> 2)) * 1024 + (c2 & 3) * 8;
  const short* Bp1 = B + (size_t)(colBase + (c1 >> 2)) * 1024 + (c1 & 3) * 8;
  const short* Bp2 = B + (size_t)(colBase + (c2 >> 2)) * 1024 + (c2 & 3) * 8;
  char* AsB = (char*)As;
  char* BsB = (char*)Bs;

  for (int k0 = 0; k0 < 1024; k0 += 32) {
    __syncthreads();
    gload_lds16(Ap1 + k0, AsB + w * 1024);
    gload_lds16(Ap2 + k0, AsB + 4096 + w * 1024);
    gload_lds16(Bp1 + k0, BsB + w * 1024);
    gload_lds16(Bp2 + k0, BsB + 4096 + w * 1024);
    asm volatile("s_waitcnt vmcnt(0)" ::: "memory");
    __syncthreads();
    bf16x8 af[4], bfr[4];
#pragma unroll
    for (int m = 0; m < 4; ++m)
      af[m] = *reinterpret_cast<const bf16x8*>(
          &As[(wr * 64 + m * 16 + l15) * 32 + lg * 8]);
#pragma unroll
    for (int n = 0; n < 4; ++n)
      bfr[n] = *reinterpret_cast<const bf16x8*>(
          &Bs[(wc * 64 + n * 16 + l15) * 32 + lg * 8]);
#pragma unroll
    for (int m = 0; m < 4; ++m)
#pragma unroll
      for (int n = 0; n < 4; ++n)
        acc[m][n] =
            __builtin_amdgcn_mfma_f32_16x16x32_bf16(af[m], bfr[n], acc[m][n], 0, 0, 0);
  }

#pragma unroll
  for (int m = 0; m < 4; ++m)
#pragma unroll
    for (int n = 0; n < 4; ++n) {
      int col = colBase + wc * 64 + n * 16 + l15;
#pragma unroll
      for (int r = 0; r < 4; ++r) {
        int row = rowBase + wr * 64 + m * 16 + lg * 4 + r;
        if (OUTF32)
          ((float*)Cv)[(size_t)row * 1024 + col] = acc[m][n][r];
        else
          ((short*)Cv + (size_t)blockIdx.z * cz)[(size_t)row * 1024 + col] =
              f2b(acc[m][n][r]);
      }
    }
}

// ---------------- flash attention ----------------
// flat grid 1024 with bijective XCD swizzle (T1): each XCD gets 4 contiguous
// bh (2 MB K+V working set, fits 4 MB per-XCD L2) x all 32 q-tiles.
// 4 waves/block, 16 q-rows per wave, 64-kv tiles.
__global__ __launch_bounds__(256) void k_attn(const short* __restrict__ Qb,
                                              const short* __restrict__ Kb,
                                              const short* __restrict__ Vt,
                                              const float* __restrict__ biasTab,
                                              short* __restrict__ Ob) {
  // dispatch id j lands on XCD j%8; orig = (j%8)*128 + j/8 gives XCD x the
  // contiguous orig-chunk [x*128,(x+1)*128) = bh in [x*4,(x+1)*4).
  const int j = blockIdx.x;
  const int orig = (j & 7) * 128 + (j >> 3);
  const int qt = orig & 31, bh = orig >> 5;
  const int b = bh >> 4, h = bh & 15;
  const int w = threadIdx.x >> 6, lane = threadIdx.x & 63;
  const int lg = lane >> 4, l15 = lane & 15;
  const int qbase = qt * 64 + w * 16;

  __shared__ __align__(16) short Plds[4][16 * 64];
  short* Pw = &Plds[w][0];

  const short* Qrow = Qb + (size_t)(b * SEQ + qbase + l15) * HD + h * 64 + lg * 8;
  bf16x8 q0 = *reinterpret_cast<const bf16x8*>(Qrow);
  bf16x8 q1 = *reinterpret_cast<const bf16x8*>(Qrow + 32);

  const short* Kbase = Kb + (size_t)(b * SEQ) * HD + h * 64;
  const short* Vbase = Vt + (size_t)bh * DK * SEQ;
  const float* btab = biasTab + h * 4096 + 2047;

  f32x4 o[4];
  float m_r[4], l_r[4];
#pragma unroll
  for (int c = 0; c < 4; ++c) o[c] = (f32x4){0.f, 0.f, 0.f, 0.f};
#pragma unroll
  for (int r = 0; r < 4; ++r) { m_r[r] = -INFINITY; l_r[r] = 0.f; }

  const f32x4 z4 = (f32x4){0.f, 0.f, 0.f, 0.f};

  for (int kt = 0; kt < 32; ++kt) {
    const int kvb = kt * 64;
    // ---- S = Q K^T
    f32x4 s[4];
#pragma unroll
    for (int c = 0; c < 4; ++c) {
      const short* kp = Kbase + (size_t)(kvb + c * 16 + l15) * HD + lg * 8;
      bf16x8 kf0 = *reinterpret_cast<const bf16x8*>(kp);
      bf16x8 kf1 = *reinterpret_cast<const bf16x8*>(kp + 32);
      s[c] = __builtin_amdgcn_mfma_f32_16x16x32_bf16(q0, kf0, z4, 0, 0, 0);
      s[c] = __builtin_amdgcn_mfma_f32_16x16x32_bf16(q1, kf1, s[c], 0, 0, 0);
    }
    // ---- + bias
#pragma unroll
    for (int c = 0; c < 4; ++c) {
      int kvg = kvb + c * 16 + l15;
#pragma unroll
      for (int r = 0; r < 4; ++r)
        s[c][r] += btab[kvg - (qbase + lg * 4 + r)];
    }
    // ---- row max (4 regs x 4 c-blocks, then across the 16-lane l15 group)
    float mx[4];
#pragma unroll
    for (int r = 0; r < 4; ++r) {
      mx[r] = fmaxf(fmaxf(s[0][r], s[1][r]), fmaxf(s[2][r], s[3][r]));
#pragma unroll
      for (int d = 1; d < 16; d <<= 1) mx[r] = fmaxf(mx[r], __shfl_xor(mx[r], d, 64));
    }
    float sc[4];
#pragma unroll
    for (int r = 0; r < 4; ++r) {
      float mn = fmaxf(m_r[r], mx[r]);
      sc[r] = __expf(m_r[r] - mn);
      m_r[r] = mn;
    }
    // ---- P = exp(S - m), row sums, rescale O and l
    float rs[4];
#pragma unroll
    for (int r = 0; r < 4; ++r) rs[r] = 0.f;
#pragma unroll
    for (int c = 0; c < 4; ++c)
#pragma unroll
      for (int r = 0; r < 4; ++r) {
        float p = __expf(s[c][r] - m_r[r]);
        s[c][r] = p;
        rs[r] += p;
      }
#pragma unroll
    for (int r = 0; r < 4; ++r) {
#pragma unroll
      for (int d = 1; d < 16; d <<= 1) rs[r] += __shfl_xor(rs[r], d, 64);
      l_r[r] = l_r[r] * sc[r] + rs[r];
    }
#pragma unroll
    for (int c = 0; c < 4; ++c)
#pragma unroll
      for (int r = 0; r < 4; ++r) o[c][r] *= sc[r];
    // ---- P -> LDS (D-layout write), reload as A-frags (per-wave region)
#pragma unroll
    for (int c = 0; c < 4; ++c)
#pragma unroll
      for (int r = 0; r < 4; ++r)
        Pw[(lg * 4 + r) * 64 + c * 16 + l15] = f2b(s[c][r]);
    asm volatile("s_waitcnt lgkmcnt(0)" ::: "memory");
    bf16x8 pa0 = *reinterpret_cast<const bf16x8*>(&Pw[l15 * 64 + lg * 8]);
    bf16x8 pa1 = *reinterpret_cast<const bf16x8*>(&Pw[l15 * 64 + 32 + lg * 8]);
    // ---- O += P V
#pragma unroll
    for (int c = 0; c < 4; ++c) {
      const short* vp = Vbase + (size_t)(c * 16 + l15) * SEQ + kvb + lg * 8;
      bf16x8 vf0 = *reinterpret_cast<const bf16x8*>(vp);
      bf16x8 vf1 = *reinterpret_cast<const bf16x8*>(vp + 32);
      o[c] = __builtin_amdgcn_mfma_f32_16x16x32_bf16(pa0, vf0, o[c], 0, 0, 0);
      o[c] = __builtin_amdgcn_mfma_f32_16x16x32_bf16(pa1, vf1, o[c], 0, 0, 0);
    }
  }
  // ---- epilogue
#pragma unroll
  for (int r = 0; r < 4; ++r) {
    float inv = 1.0f / l_r[r];
    int row = b * SEQ + qbase + lg * 4 + r;
#pragma unroll
    for (int c = 0; c < 4; ++c)
      Ob[(size_t)row * HD + h * 64 + c * 16 + l15] = f2b(o[c][r] * inv);
  }
}

// ---------------- launch ----------------
extern "C" void kernel_launch(void* const* d_in, const int* in_sizes, int n_in,
                              void* d_out, int out_size, void* d_ws, size_t ws_size,
                              hipStream_t stream) {
  const float* H    = (const float*)d_in[0];
  const float* Wq   = (const float*)d_in[1];
  const float* Wk   = (const float*)d_in[2];
  const float* Wv   = (const float*)d_in[3];
  const float* Wo   = (const float*)d_in[4];
  const float* relb = (const float*)d_in[5];

  char* ws = (char*)d_ws;
  short* Hb   = (short*)(ws);                        // 8 MB
  short* Wts  = (short*)(ws + ((size_t)8 << 20));    // 4 x 2 MB (WqT WkT WvT WoT)
  short* Qb   = (short*)(ws + ((size_t)16 << 20));   // 8 MB
  short* Kb   = (short*)(ws + ((size_t)24 << 20));   // 8 MB  (contiguous after Qb)
  short* Vb   = (short*)(ws + ((size_t)32 << 20));   // 8 MB  (contiguous after Kb)
  short* Vt   = (short*)(ws + ((size_t)40 << 20));   // 8 MB
  short* Ob   = (short*)(ws + ((size_t)48 << 20));   // 8 MB
  float* btab = (float*)(ws + ((size_t)56 << 20));   // 256 KB

  k_cvt_h<<<2048, 256, 0, stream>>>(H, Hb);
  k_wtrans<<<dim3(32, 32, 4), 256, 0, stream>>>(Wq, Wk, Wv, Wo, Wts);
  k_bias<<<256, 256, 0, stream>>>(relb, btab);

  // QKV fused over z: C = Hb * W{q,k,v}^T  (writes Qb, Kb, Vb via cz stride)
  k_gemm_bt<0><<<dim3(8, 32, 3), 256, 0, stream>>>(
      Hb, Wts, Qb, (size_t)1024 * 1024, (size_t)4096 * 1024);

  k_vtrans<<<dim3(32, 32), 256, 0, stream>>>(Vb, Vt);
  k_attn<<<1024, 256, 0, stream>>>(Qb, Kb, Vt, btab, Ob);

  // out = Ob * Wo^T
  k_gemm_bt<1><<<dim3(8, 32, 1), 256, 0, stream>>>(
      Ob, Wts + (size_t)3 * 1024 * 1024, d_out, 0, 0);
}

// Round 3
// 382.464 us; speedup vs baseline: 1.1060x; 1.1060x over previous
//
#include <hip/hip_runtime.h>
#include <hip/hip_bf16.h>
#include <math.h>

#define DM   1024
#define HD   1024
#define NH   16
#define DK   64
#define SEQ  2048
#define BATCH 2

typedef __attribute__((ext_vector_type(8))) short bf16x8;
typedef __attribute__((ext_vector_type(4))) float f32x4;

static __device__ __forceinline__ short f2b(float f) {
  union { float f; unsigned u; } v; v.f = f;
  unsigned r = (v.u + 0x7fffu + ((v.u >> 16) & 1u)) >> 16;
  return (short)r;
}

static __device__ __forceinline__ void gload_lds16(const void* g, void* l) {
  __builtin_amdgcn_global_load_lds(
      (const __attribute__((address_space(1))) void*)g,
      (__attribute__((address_space(3))) void*)l, 16, 0, 0);
}

// ---------------- prep kernels ----------------

__global__ __launch_bounds__(256) void k_cvt_h(const float* __restrict__ in,
                                               short* __restrict__ out) {
  int i = (blockIdx.x * 256 + threadIdx.x) * 8;
  float4 a = *reinterpret_cast<const float4*>(in + i);
  float4 b = *reinterpret_cast<const float4*>(in + i + 4);
  bf16x8 o;
  o[0] = f2b(a.x); o[1] = f2b(a.y); o[2] = f2b(a.z); o[3] = f2b(a.w);
  o[4] = f2b(b.x); o[5] = f2b(b.y); o[6] = f2b(b.z); o[7] = f2b(b.w);
  *reinterpret_cast<bf16x8*>(out + i) = o;
}

// transpose + convert 1024x1024 fp32 [K][N] -> bf16 [N][K]; z selects matrix
__global__ __launch_bounds__(256) void k_wtrans(const float* __restrict__ Wq,
                                                const float* __restrict__ Wk,
                                                const float* __restrict__ Wv,
                                                const float* __restrict__ Wo,
                                                short* __restrict__ Wts) {
  const float* src = (blockIdx.z == 0) ? Wq : (blockIdx.z == 1) ? Wk
                   : (blockIdx.z == 2) ? Wv : Wo;
  short* dst = Wts + (size_t)blockIdx.z * DM * HD;
  __shared__ float t[32][33];
  int tx = threadIdx.x & 31, ty = threadIdx.x >> 5;  // ty 0..7
  int k0 = blockIdx.y * 32, n0 = blockIdx.x * 32;
#pragma unroll
  for (int i = 0; i < 4; ++i)
    t[ty + i * 8][tx] = src[(size_t)(k0 + ty + i * 8) * 1024 + n0 + tx];
  __syncthreads();
#pragma unroll
  for (int i = 0; i < 4; ++i)
    dst[(size_t)(n0 + ty + i * 8) * 1024 + k0 + tx] = f2b(t[tx][ty + i * 8]);
}

// bias table: btab[h][pos], pos = delta + 2047, delta = kv - q
__global__ __launch_bounds__(256) void k_bias(const float* __restrict__ rel_bias,
                                              float* __restrict__ btab) {
  int idx = blockIdx.x * 256 + threadIdx.x;  // 65536
  int h = idx >> 12, pos = idx & 4095;
  int delta = pos - 2047;
  int rb = (delta > 0) ? 16 : 0;
  int ar = (delta < 0) ? -delta : delta;
  int bb;
  if (ar < 8) bb = ar;
  else {
    bb = 8 + (int)(logf((float)ar * 0.125f) * (8.0f / 2.7725887222397811f));
    if (bb > 15) bb = 15;
  }
  btab[idx] = rel_bias[(rb + bb) * NH + h];
}

// V [4096][1024] bf16 -> Vt[bh][dk=64][seq=2048] bf16
__global__ __launch_bounds__(256) void k_vtrans(const short* __restrict__ Vb,
                                                short* __restrict__ Vt) {
  int bh = blockIdx.y, b = bh >> 4, h = bh & 15;
  int st = blockIdx.x * 64;
  __shared__ short t[64][72];
  int tx = threadIdx.x & 15, ty = threadIdx.x >> 4;
#pragma unroll
  for (int i = 0; i < 4; ++i) {
    int row = ty + i * 16;
    *reinterpret_cast<short4*>(&t[row][tx * 4]) =
        *reinterpret_cast<const short4*>(
            &Vb[(size_t)(b * SEQ + st + row) * HD + h * 64 + tx * 4]);
  }
  __syncthreads();
#pragma unroll
  for (int i = 0; i < 4; ++i) {
    int dk = ty + i * 16;
    short4 v = make_short4(t[tx * 4 + 0][dk], t[tx * 4 + 1][dk],
                           t[tx * 4 + 2][dk], t[tx * 4 + 3][dk]);
    *reinterpret_cast<short4*>(
        &Vt[(size_t)bh * DK * SEQ + (size_t)dk * SEQ + st + tx * 4]) = v;
  }
}

// ---------------- GEMM: C[M][1024] = A[M][1024]bf16 * Bt[1024][1024]bf16^T ----
// 128x128 tile, 4 waves (2x2), K-step 32, global_load_lds staging (m97 form)
template <int OUTF32>
__global__ __launch_bounds__(256) void k_gemm_bt(const short* __restrict__ A,
                                                 const short* __restrict__ Bt,
                                                 void* __restrict__ Cv,
                                                 size_t btz, size_t cz) {
  __shared__ __align__(16) short As[128 * 32];
  __shared__ __align__(16) short Bs[128 * 32];
  const int tid = threadIdx.x, w = tid >> 6, lane = tid & 63;
  const int wr = w >> 1, wc = w & 1, lg = lane >> 4, l15 = lane & 15;
  const int rowBase = blockIdx.y * 128, colBase = blockIdx.x * 128;
  const short* B = Bt + (size_t)blockIdx.z * btz;

  f32x4 acc[4][4];
#pragma unroll
  for (int m = 0; m < 4; ++m)
#pragma unroll
    for (int n = 0; n < 4; ++n) acc[m][n] = (f32x4){0.f, 0.f, 0.f, 0.f};

  const int c1 = w * 64 + lane, c2 = c1 + 256;
  const short* Ap1 = A + (size_t)(rowBase + (c1 >> 2)) * 1024 + (c1 & 3) * 8;
  const short* Ap2 = A + (size_t)(rowBase + (c2 >> 2)) * 1024 + (c2 & 3) * 8;
  const short* Bp1 = B + (size_t)(colBase + (c1 >> 2)) * 1024 + (c1 & 3) * 8;
  const short* Bp2 = B + (size_t)(colBase + (c2 >> 2)) * 1024 + (c2 & 3) * 8;
  char* AsB = (char*)As;
  char* BsB = (char*)Bs;

  for (int k0 = 0; k0 < 1024; k0 += 32) {
    __syncthreads();
    gload_lds16(Ap1 + k0, AsB + w * 1024);
    gload_lds16(Ap2 + k0, AsB + 4096 + w * 1024);
    gload_lds16(Bp1 + k0, BsB + w * 1024);
    gload_lds16(Bp2 + k0, BsB + 4096 + w * 1024);
    asm volatile("s_waitcnt vmcnt(0)" ::: "memory");
    __syncthreads();
    bf16x8 af[4], bfr[4];
#pragma unroll
    for (int m = 0; m < 4; ++m)
      af[m] = *reinterpret_cast<const bf16x8*>(
          &As[(wr * 64 + m * 16 + l15) * 32 + lg * 8]);
#pragma unroll
    for (int n = 0; n < 4; ++n)
      bfr[n] = *reinterpret_cast<const bf16x8*>(
          &Bs[(wc * 64 + n * 16 + l15) * 32 + lg * 8]);
#pragma unroll
    for (int m = 0; m < 4; ++m)
#pragma unroll
      for (int n = 0; n < 4; ++n)
        acc[m][n] =
            __builtin_amdgcn_mfma_f32_16x16x32_bf16(af[m], bfr[n], acc[m][n], 0, 0, 0);
  }

#pragma unroll
  for (int m = 0; m < 4; ++m)
#pragma unroll
    for (int n = 0; n < 4; ++n) {
      int col = colBase + wc * 64 + n * 16 + l15;
#pragma unroll
      for (int r = 0; r < 4; ++r) {
        int row = rowBase + wr * 64 + m * 16 + lg * 4 + r;
        if (OUTF32)
          ((float*)Cv)[(size_t)row * 1024 + col] = acc[m][n][r];
        else
          ((short*)Cv + (size_t)blockIdx.z * cz)[(size_t)row * 1024 + col] =
              f2b(acc[m][n][r]);
      }
    }
}

// ---------------- flash attention (swapped-operand form) ----------------
// grid 1024 flat, bijective XCD swizzle. 4 waves/block, 16 q-rows/wave.
// QK^T computed as mfma(K,Q) -> S^T frag: col=l15=q-row, row=kv. Each lane
// owns ONE q-row => softmax reduce = 15 in-reg ops + 2 shfl_xor (d=16,32).
// PV as mfma(Vt,P) -> O^T frag. P bounced through XOR-swizzled LDS.
__global__ __launch_bounds__(256) void k_attn(const short* __restrict__ Qb,
                                              const short* __restrict__ Kb,
                                              const short* __restrict__ Vt,
                                              const float* __restrict__ biasTab,
                                              short* __restrict__ Ob) {
  const int j = blockIdx.x;
  const int orig = (j & 7) * 128 + (j >> 3);
  const int qt = orig & 31, bh = orig >> 5;
  const int b = bh >> 4, h = bh & 15;
  const int w = threadIdx.x >> 6, lane = threadIdx.x & 63;
  const int lg = lane >> 4, l15 = lane & 15;
  const int qbase = qt * 64 + w * 16;

  __shared__ __align__(16) short Plds[4][16 * 64];
  char* PwB = (char*)(&Plds[w][0]);
  const int swz = (l15 & 7) << 4;

  const short* Qrow = Qb + (size_t)(b * SEQ + qbase + l15) * HD + h * 64 + lg * 8;
  bf16x8 q0 = *reinterpret_cast<const bf16x8*>(Qrow);
  bf16x8 q1 = *reinterpret_cast<const bf16x8*>(Qrow + 32);

  const short* Kbase = Kb + (size_t)(b * SEQ) * HD + h * 64;
  const short* Vbase = Vt + (size_t)bh * DK * SEQ;
  const float* btab = biasTab + h * 4096 + 2047;
  const float bias_hi = btab[1024];   // saturated delta >= +91
  const float bias_lo = btab[-1024];  // saturated delta <= -91

  f32x4 o[4];
#pragma unroll
  for (int c = 0; c < 4; ++c) o[c] = (f32x4){0.f, 0.f, 0.f, 0.f};
  float m_r = -INFINITY, l_r = 0.f;

  const f32x4 z4 = (f32x4){0.f, 0.f, 0.f, 0.f};
  // swizzled P read offsets (must apply XOR to full offset, not add after)
  const int rb0 = (l15 * 128 + lg * 16) ^ swz;
  const int rb1 = (l15 * 128 + 64 + lg * 16) ^ swz;

  for (int kt = 0; kt < 32; ++kt) {
    const int kvb = kt * 64;
    const int dkv = kvb - qbase;
    // ---- S^T = K Q^T : col=q(l15), row=kv(c*16+lg*4+r)
    f32x4 s[4];
#pragma unroll
    for (int c = 0; c < 4; ++c) {
      const short* kp = Kbase + (size_t)(kvb + c * 16 + l15) * HD + lg * 8;
      bf16x8 kf0 = *reinterpret_cast<const bf16x8*>(kp);
      bf16x8 kf1 = *reinterpret_cast<const bf16x8*>(kp + 32);
      s[c] = __builtin_amdgcn_mfma_f32_16x16x32_bf16(kf0, q0, z4, 0, 0, 0);
      s[c] = __builtin_amdgcn_mfma_f32_16x16x32_bf16(kf1, q1, s[c], 0, 0, 0);
    }
    // ---- + bias (saturated-tile fast path: wave-uniform branch)
    if (dkv >= 112) {
#pragma unroll
      for (int c = 0; c < 4; ++c)
#pragma unroll
        for (int r = 0; r < 4; ++r) s[c][r] += bias_hi;
    } else if (dkv <= -160) {
#pragma unroll
      for (int c = 0; c < 4; ++c)
#pragma unroll
        for (int r = 0; r < 4; ++r) s[c][r] += bias_lo;
    } else {
#pragma unroll
      for (int c = 0; c < 4; ++c)
#pragma unroll
        for (int r = 0; r < 4; ++r)
          s[c][r] += btab[dkv + c * 16 + lg * 4 + r - l15];
    }
    // ---- row max: in-register over 16, then 2 cross-lane steps
    float mx = s[0][0];
#pragma unroll
    for (int c = 0; c < 4; ++c)
#pragma unroll
      for (int r = 0; r < 4; ++r) mx = fmaxf(mx, s[c][r]);
    mx = fmaxf(mx, __shfl_xor(mx, 16, 64));
    mx = fmaxf(mx, __shfl_xor(mx, 32, 64));
    float mn = fmaxf(m_r, mx);
    float sc = __expf(m_r - mn);
    m_r = mn;
    // ---- P = exp(S - m), row sum
    float rs = 0.f;
#pragma unroll
    for (int c = 0; c < 4; ++c)
#pragma unroll
      for (int r = 0; r < 4; ++r) {
        float p = __expf(s[c][r] - m_r);
        s[c][r] = p;
        rs += p;
      }
    rs += __shfl_xor(rs, 16, 64);
    rs += __shfl_xor(rs, 32, 64);
    l_r = l_r * sc + rs;
#pragma unroll
    for (int c = 0; c < 4; ++c)
#pragma unroll
      for (int r = 0; r < 4; ++r) o[c][r] *= sc;
    // ---- P -> LDS: pack 4 consecutive kv (r) into one b64, XOR-swizzled
#pragma unroll
    for (int c = 0; c < 4; ++c) {
      short4 pk;
      pk.x = f2b(s[c][0]); pk.y = f2b(s[c][1]);
      pk.z = f2b(s[c][2]); pk.w = f2b(s[c][3]);
      int byte = (l15 * 128 + c * 32 + lg * 8) ^ swz;
      *reinterpret_cast<short4*>(PwB + byte) = pk;
    }
    asm volatile("s_waitcnt lgkmcnt(0)" ::: "memory");
    bf16x8 pb0 = *reinterpret_cast<const bf16x8*>(PwB + rb0);
    bf16x8 pb1 = *reinterpret_cast<const bf16x8*>(PwB + rb1);
    // ---- O^T += V^T P^T : A=Vt rows dk, B=P cols q
#pragma unroll
    for (int c = 0; c < 4; ++c) {
      const short* vp = Vbase + (size_t)(c * 16 + l15) * SEQ + kvb + lg * 8;
      bf16x8 vf0 = *reinterpret_cast<const bf16x8*>(vp);
      bf16x8 vf1 = *reinterpret_cast<const bf16x8*>(vp + 32);
      o[c] = __builtin_amdgcn_mfma_f32_16x16x32_bf16(vf0, pb0, o[c], 0, 0, 0);
      o[c] = __builtin_amdgcn_mfma_f32_16x16x32_bf16(vf1, pb1, o[c], 0, 0, 0);
    }
  }
  // ---- epilogue: lane owns q=qbase+l15; o[c][r] = O[dk=c*16+lg*4+r][q]
  float inv = 1.0f / l_r;
  const size_t orow = (size_t)(b * SEQ + qbase + l15) * HD + h * 64;
#pragma unroll
  for (int c = 0; c < 4; ++c) {
    short4 pk;
    pk.x = f2b(o[c][0] * inv); pk.y = f2b(o[c][1] * inv);
    pk.z = f2b(o[c][2] * inv); pk.w = f2b(o[c][3] * inv);
    *reinterpret_cast<short4*>(&Ob[orow + c * 16 + lg * 4]) = pk;
  }
}

// ---------------- launch ----------------
extern "C" void kernel_launch(void* const* d_in, const int* in_sizes, int n_in,
                              void* d_out, int out_size, void* d_ws, size_t ws_size,
                              hipStream_t stream) {
  const float* H    = (const float*)d_in[0];
  const float* Wq   = (const float*)d_in[1];
  const float* Wk   = (const float*)d_in[2];
  const float* Wv   = (const float*)d_in[3];
  const float* Wo   = (const float*)d_in[4];
  const float* relb = (const float*)d_in[5];

  char* ws = (char*)d_ws;
  short* Hb   = (short*)(ws);                        // 8 MB
  short* Wts  = (short*)(ws + ((size_t)8 << 20));    // 4 x 2 MB (WqT WkT WvT WoT)
  short* Qb   = (short*)(ws + ((size_t)16 << 20));   // 8 MB
  short* Kb   = (short*)(ws + ((size_t)24 << 20));   // 8 MB
  short* Vb   = (short*)(ws + ((size_t)32 << 20));   // 8 MB
  short* Vt   = (short*)(ws + ((size_t)40 << 20));   // 8 MB
  short* Ob   = (short*)(ws + ((size_t)48 << 20));   // 8 MB
  float* btab = (float*)(ws + ((size_t)56 << 20));   // 256 KB

  k_cvt_h<<<2048, 256, 0, stream>>>(H, Hb);
  k_wtrans<<<dim3(32, 32, 4), 256, 0, stream>>>(Wq, Wk, Wv, Wo, Wts);
  k_bias<<<256, 256, 0, stream>>>(relb, btab);

  // QKV fused over z: C = Hb * W{q,k,v}^T  (writes Qb, Kb, Vb via cz stride)
  k_gemm_bt<0><<<dim3(8, 32, 3), 256, 0, stream>>>(
      Hb, Wts, Qb, (size_t)1024 * 1024, (size_t)4096 * 1024);

  k_vtrans<<<dim3(32, 32), 256, 0, stream>>>(Vb, Vt);
  k_attn<<<1024, 256, 0, stream>>>(Qb, Kb, Vt, btab, Ob);

  // out = Ob * Wo^T
  k_gemm_bt<1><<<dim3(8, 32, 1), 256, 0, stream>>>(
      Ob, Wts + (size_t)3 * 1024 * 1024, d_out, 0, 0);
}

// Round 5
// 223.613 us; speedup vs baseline: 1.8917x; 1.7104x over previous
//
#include <hip/hip_runtime.h>
#include <hip/hip_bf16.h>
#include <math.h>

#define DM   1024
#define HD   1024
#define NH   16
#define DK   64
#define SEQ  2048
#define BATCH 2

typedef __attribute__((ext_vector_type(8))) short bf16x8;
typedef __attribute__((ext_vector_type(4))) float f32x4;

static __device__ __forceinline__ short f2b(float f) {
  union { float f; unsigned u; } v; v.f = f;
  unsigned r = (v.u + 0x7fffu + ((v.u >> 16) & 1u)) >> 16;
  return (short)r;
}

static __device__ __forceinline__ void gload_lds16(const void* g, void* l) {
  __builtin_amdgcn_global_load_lds(
      (const __attribute__((address_space(1))) void*)g,
      (__attribute__((address_space(3))) void*)l, 16, 0, 0);
}

// ---------------- prep kernels ----------------

__global__ __launch_bounds__(256) void k_cvt_h(const float* __restrict__ in,
                                               short* __restrict__ out) {
  int i = (blockIdx.x * 256 + threadIdx.x) * 8;
  float4 a = *reinterpret_cast<const float4*>(in + i);
  float4 b = *reinterpret_cast<const float4*>(in + i + 4);
  bf16x8 o;
  o[0] = f2b(a.x); o[1] = f2b(a.y); o[2] = f2b(a.z); o[3] = f2b(a.w);
  o[4] = f2b(b.x); o[5] = f2b(b.y); o[6] = f2b(b.z); o[7] = f2b(b.w);
  *reinterpret_cast<bf16x8*>(out + i) = o;
}

// transpose + convert 1024x1024 fp32 [K][N] -> bf16 [N][K]; z selects matrix
__global__ __launch_bounds__(256) void k_wtrans(const float* __restrict__ Wq,
                                                const float* __restrict__ Wk,
                                                const float* __restrict__ Wv,
                                                const float* __restrict__ Wo,
                                                short* __restrict__ Wts) {
  const float* src = (blockIdx.z == 0) ? Wq : (blockIdx.z == 1) ? Wk
                   : (blockIdx.z == 2) ? Wv : Wo;
  short* dst = Wts + (size_t)blockIdx.z * DM * HD;
  __shared__ float t[32][33];
  int tx = threadIdx.x & 31, ty = threadIdx.x >> 5;  // ty 0..7
  int k0 = blockIdx.y * 32, n0 = blockIdx.x * 32;
#pragma unroll
  for (int i = 0; i < 4; ++i)
    t[ty + i * 8][tx] = src[(size_t)(k0 + ty + i * 8) * 1024 + n0 + tx];
  __syncthreads();
#pragma unroll
  for (int i = 0; i < 4; ++i)
    dst[(size_t)(n0 + ty + i * 8) * 1024 + k0 + tx] = f2b(t[tx][ty + i * 8]);
}

// bias table: btab[h][pos], pos = delta + 2047, delta = kv - q
__global__ __launch_bounds__(256) void k_bias(const float* __restrict__ rel_bias,
                                              float* __restrict__ btab) {
  int idx = blockIdx.x * 256 + threadIdx.x;  // 65536
  int h = idx >> 12, pos = idx & 4095;
  int delta = pos - 2047;
  int rb = (delta > 0) ? 16 : 0;
  int ar = (delta < 0) ? -delta : delta;
  int bb;
  if (ar < 8) bb = ar;
  else {
    bb = 8 + (int)(logf((float)ar * 0.125f) * (8.0f / 2.7725887222397811f));
    if (bb > 15) bb = 15;
  }
  btab[idx] = rel_bias[(rb + bb) * NH + h];
}

// V [4096][1024] bf16 -> Vt[bh][dk=64][seq=2048] bf16
__global__ __launch_bounds__(256) void k_vtrans(const short* __restrict__ Vb,
                                                short* __restrict__ Vt) {
  int bh = blockIdx.y, b = bh >> 4, h = bh & 15;
  int st = blockIdx.x * 64;
  __shared__ short t[64][72];
  int tx = threadIdx.x & 15, ty = threadIdx.x >> 4;
#pragma unroll
  for (int i = 0; i < 4; ++i) {
    int row = ty + i * 16;
    *reinterpret_cast<short4*>(&t[row][tx * 4]) =
        *reinterpret_cast<const short4*>(
            &Vb[(size_t)(b * SEQ + st + row) * HD + h * 64 + tx * 4]);
  }
  __syncthreads();
#pragma unroll
  for (int i = 0; i < 4; ++i) {
    int dk = ty + i * 16;
    short4 v = make_short4(t[tx * 4 + 0][dk], t[tx * 4 + 1][dk],
                           t[tx * 4 + 2][dk], t[tx * 4 + 3][dk]);
    *reinterpret_cast<short4*>(
        &Vt[(size_t)bh * DK * SEQ + (size_t)dk * SEQ + st + tx * 4]) = v;
  }
}

// ---------------- GEMM: C[M][1024] = A[M][1024]bf16 * Bt[1024][1024]bf16^T ----
template <int OUTF32>
__global__ __launch_bounds__(256) void k_gemm_bt(const short* __restrict__ A,
                                                 const short* __restrict__ Bt,
                                                 void* __restrict__ Cv,
                                                 size_t btz, size_t cz) {
  __shared__ __align__(16) short As[128 * 32];
  __shared__ __align__(16) short Bs[128 * 32];
  const int tid = threadIdx.x, w = tid >> 6, lane = tid & 63;
  const int wr = w >> 1, wc = w & 1, lg = lane >> 4, l15 = lane & 15;
  const int rowBase = blockIdx.y * 128, colBase = blockIdx.x * 128;
  const short* B = Bt + (size_t)blockIdx.z * btz;

  f32x4 acc[4][4];
#pragma unroll
  for (int m = 0; m < 4; ++m)
#pragma unroll
    for (int n = 0; n < 4; ++n) acc[m][n] = (f32x4){0.f, 0.f, 0.f, 0.f};

  const int c1 = w * 64 + lane, c2 = c1 + 256;
  const short* Ap1 = A + (size_t)(rowBase + (c1 >> 2)) * 1024 + (c1 & 3) * 8;
  const short* Ap2 = A + (size_t)(rowBase + (c2 >> 2)) * 1024 + (c2 & 3) * 8;
  const short* Bp1 = B + (size_t)(colBase + (c1 >> 2)) * 1024 + (c1 & 3) * 8;
  const short* Bp2 = B + (size_t)(colBase + (c2 >> 2)) * 1024 + (c2 & 3) * 8;
  char* AsB = (char*)As;
  char* BsB = (char*)Bs;

  for (int k0 = 0; k0 < 1024; k0 += 32) {
    __syncthreads();
    gload_lds16(Ap1 + k0, AsB + w * 1024);
    gload_lds16(Ap2 + k0, AsB + 4096 + w * 1024);
    gload_lds16(Bp1 + k0, BsB + w * 1024);
    gload_lds16(Bp2 + k0, BsB + 4096 + w * 1024);
    asm volatile("s_waitcnt vmcnt(0)" ::: "memory");
    __syncthreads();
    bf16x8 af[4], bfr[4];
#pragma unroll
    for (int m = 0; m < 4; ++m)
      af[m] = *reinterpret_cast<const bf16x8*>(
          &As[(wr * 64 + m * 16 + l15) * 32 + lg * 8]);
#pragma unroll
    for (int n = 0; n < 4; ++n)
      bfr[n] = *reinterpret_cast<const bf16x8*>(
          &Bs[(wc * 64 + n * 16 + l15) * 32 + lg * 8]);
#pragma unroll
    for (int m = 0; m < 4; ++m)
#pragma unroll
      for (int n = 0; n < 4; ++n)
        acc[m][n] =
            __builtin_amdgcn_mfma_f32_16x16x32_bf16(af[m], bfr[n], acc[m][n], 0, 0, 0);
  }

#pragma unroll
  for (int m = 0; m < 4; ++m)
#pragma unroll
    for (int n = 0; n < 4; ++n) {
      int col = colBase + wc * 64 + n * 16 + l15;
#pragma unroll
      for (int r = 0; r < 4; ++r) {
        int row = rowBase + wr * 64 + m * 16 + lg * 4 + r;
        if (OUTF32)
          ((float*)Cv)[(size_t)row * 1024 + col] = acc[m][n][r];
        else
          ((short*)Cv + (size_t)blockIdx.z * cz)[(size_t)row * 1024 + col] =
              f2b(acc[m][n][r]);
      }
    }
}

// ---------------- flash attention (LDS-staged, double-buffered) -------------
// Tiles: LDS(row, cb) = G(row, cb ^ ((row&7)<<4)) — linear gload_lds dest,
// inverse-swizzled per-lane global source, swizzled ds_read (rule 21 / T2).
// Wave w stages rows w*16..w*16+15 (2 instr of 8 rows each).
static __device__ __forceinline__ void stage_tile(const char* gbase, size_t grs,
                                                  char* lbase, int w, int lane) {
  const int r0 = w * 16 + (lane >> 3);
  const int cb = (lane & 7) * 16;
  const int sw = (r0 & 7) << 4;  // (r0+8)&7 == r0&7
  gload_lds16(gbase + (size_t)r0 * grs + (cb ^ sw), lbase + w * 2048);
  gload_lds16(gbase + (size_t)(r0 + 8) * grs + (cb ^ sw), lbase + w * 2048 + 1024);
}

__global__ __launch_bounds__(256, 4) void k_attn(const short* __restrict__ Qb,
                                                 const short* __restrict__ Kb,
                                                 const short* __restrict__ Vt,
                                                 const float* __restrict__ biasTab,
                                                 short* __restrict__ Ob) {
  const int j = blockIdx.x;
  const int orig = (j & 7) * 128 + (j >> 3);  // bijective XCD swizzle (1024%8==0)
  const int qt = orig & 31, bh = orig >> 5;
  const int b = bh >> 4, h = bh & 15;
  const int w = threadIdx.x >> 6, lane = threadIdx.x & 63;
  const int lg = lane >> 4, l15 = lane & 15;
  const int qbase = qt * 64 + w * 16;

  __shared__ __align__(16) char Ks[2][8192];
  __shared__ __align__(16) char Vs[2][8192];
  __shared__ __align__(16) short Plds[4][1024];
  char* PwB = (char*)(&Plds[w][0]);
  const int swz = (l15 & 7) << 4;

  const short* Qrow = Qb + (size_t)(b * SEQ + qbase + l15) * HD + h * 64 + lg * 8;
  bf16x8 q0 = *reinterpret_cast<const bf16x8*>(Qrow);
  bf16x8 q1 = *reinterpret_cast<const bf16x8*>(Qrow + 32);

  const char* Kg = (const char*)(Kb + (size_t)(b * SEQ) * HD + h * 64);
  const char* Vg = (const char*)(Vt + (size_t)bh * DK * SEQ);
  const float* btab = biasTab + h * 4096 + 2047;
  const float bias_hi = btab[1024];   // saturated delta >= +91
  const float bias_lo = btab[-1024];  // saturated delta <= -91

  f32x4 o[4];
#pragma unroll
  for (int c = 0; c < 4; ++c) o[c] = (f32x4){0.f, 0.f, 0.f, 0.f};
  float m_r = -INFINITY, l_r = 0.f;

  const f32x4 z4 = (f32x4){0.f, 0.f, 0.f, 0.f};
  const int rb0 = (l15 * 128 + lg * 16) ^ swz;
  const int rb1 = (l15 * 128 + 64 + lg * 16) ^ swz;

  // prologue: stage tile 0
  stage_tile(Kg, 2048, Ks[0], w, lane);
  stage_tile(Vg, 4096, Vs[0], w, lane);
  asm volatile("s_waitcnt vmcnt(0)" ::: "memory");
  __syncthreads();
  int cur = 0;

  for (int kt = 0; kt < 32; ++kt) {
    const int kvb = kt * 64;
    const int dkv = kvb - qbase;
    // ---- issue next-tile staging (overlaps with this tile's compute)
    if (kt < 31) {
      stage_tile(Kg + (size_t)(kvb + 64) * 2048, 2048, Ks[cur ^ 1], w, lane);
      stage_tile(Vg + (size_t)(kvb + 64) * 2, 4096, Vs[cur ^ 1], w, lane);
    }
    // ---- S^T = K Q^T : col=q(l15), row=kv(c*16+lg*4+r)
    const char* KsC = Ks[cur];
    f32x4 s[4];
#pragma unroll
    for (int c = 0; c < 4; ++c) {
      const int krow = c * 16 + l15;
      const int ksw = (krow & 7) << 4;
      const char* kr = KsC + krow * 128;
      bf16x8 kf0 = *reinterpret_cast<const bf16x8*>(kr + ((lg * 16) ^ ksw));
      bf16x8 kf1 = *reinterpret_cast<const bf16x8*>(kr + ((64 + lg * 16) ^ ksw));
      s[c] = __builtin_amdgcn_mfma_f32_16x16x32_bf16(kf0, q0, z4, 0, 0, 0);
      s[c] = __builtin_amdgcn_mfma_f32_16x16x32_bf16(kf1, q1, s[c], 0, 0, 0);
    }
    // ---- + bias (saturated-tile fast path: wave-uniform branch)
    if (dkv >= 112) {
#pragma unroll
      for (int c = 0; c < 4; ++c)
#pragma unroll
        for (int r = 0; r < 4; ++r) s[c][r] += bias_hi;
    } else if (dkv <= -160) {
#pragma unroll
      for (int c = 0; c < 4; ++c)
#pragma unroll
        for (int r = 0; r < 4; ++r) s[c][r] += bias_lo;
    } else {
#pragma unroll
      for (int c = 0; c < 4; ++c)
#pragma unroll
        for (int r = 0; r < 4; ++r)
          s[c][r] += btab[dkv + c * 16 + lg * 4 + r - l15];
    }
    // ---- row max: in-register over 16, then 2 cross-lane steps
    float mx = s[0][0];
#pragma unroll
    for (int c = 0; c < 4; ++c)
#pragma unroll
      for (int r = 0; r < 4; ++r) mx = fmaxf(mx, s[c][r]);
    mx = fmaxf(mx, __shfl_xor(mx, 16, 64));
    mx = fmaxf(mx, __shfl_xor(mx, 32, 64));
    float mn = fmaxf(m_r, mx);
    float sc = __expf(m_r - mn);
    m_r = mn;
    // ---- P = exp(S - m), row sum
    float rs = 0.f;
#pragma unroll
    for (int c = 0; c < 4; ++c)
#pragma unroll
      for (int r = 0; r < 4; ++r) {
        float p = __expf(s[c][r] - m_r);
        s[c][r] = p;
        rs += p;
      }
    rs += __shfl_xor(rs, 16, 64);
    rs += __shfl_xor(rs, 32, 64);
    l_r = l_r * sc + rs;
#pragma unroll
    for (int c = 0; c < 4; ++c)
#pragma unroll
      for (int r = 0; r < 4; ++r) o[c][r] *= sc;
    // ---- P -> per-wave LDS (XOR-swizzled b64 writes), reload as B-frags
#pragma unroll
    for (int c = 0; c < 4; ++c) {
      short4 pk;
      pk.x = f2b(s[c][0]); pk.y = f2b(s[c][1]);
      pk.z = f2b(s[c][2]); pk.w = f2b(s[c][3]);
      int byte = (l15 * 128 + c * 32 + lg * 8) ^ swz;
      *reinterpret_cast<short4*>(PwB + byte) = pk;
    }
    // ---- V frags from staged tile
    const char* VsC = Vs[cur];
    bf16x8 vf0[4], vf1[4];
#pragma unroll
    for (int c = 0; c < 4; ++c) {
      const int vrow = c * 16 + l15;
      const int vsw = (vrow & 7) << 4;
      const char* vr = VsC + vrow * 128;
      vf0[c] = *reinterpret_cast<const bf16x8*>(vr + ((lg * 16) ^ vsw));
      vf1[c] = *reinterpret_cast<const bf16x8*>(vr + ((64 + lg * 16) ^ vsw));
    }
    asm volatile("s_waitcnt lgkmcnt(0)" ::: "memory");
    bf16x8 pb0 = *reinterpret_cast<const bf16x8*>(PwB + rb0);
    bf16x8 pb1 = *reinterpret_cast<const bf16x8*>(PwB + rb1);
    // ---- O^T += V^T P^T
#pragma unroll
    for (int c = 0; c < 4; ++c) {
      o[c] = __builtin_amdgcn_mfma_f32_16x16x32_bf16(vf0[c], pb0, o[c], 0, 0, 0);
      o[c] = __builtin_amdgcn_mfma_f32_16x16x32_bf16(vf1[c], pb1, o[c], 0, 0, 0);
    }
    // ---- staged loads landed; all waves done with [cur]
    asm volatile("s_waitcnt vmcnt(0)" ::: "memory");
    __syncthreads();
    cur ^= 1;
  }
  // ---- epilogue: lane owns q=qbase+l15; o[c][r] = O[dk=c*16+lg*4+r][q]
  float inv = 1.0f / l_r;
  const size_t orow = (size_t)(b * SEQ + qbase + l15) * HD + h * 64;
#pragma unroll
  for (int c = 0; c < 4; ++c) {
    short4 pk;
    pk.x = f2b(o[c][0] * inv); pk.y = f2b(o[c][1] * inv);
    pk.z = f2b(o[c][2] * inv); pk.w = f2b(o[c][3] * inv);
    *reinterpret_cast<short4*>(&Ob[orow + c * 16 + lg * 4]) = pk;
  }
}

// ---------------- launch ----------------
extern "C" void kernel_launch(void* const* d_in, const int* in_sizes, int n_in,
                              void* d_out, int out_size, void* d_ws, size_t ws_size,
                              hipStream_t stream) {
  const float* H    = (const float*)d_in[0];
  const float* Wq   = (const float*)d_in[1];
  const float* Wk   = (const float*)d_in[2];
  const float* Wv   = (const float*)d_in[3];
  const float* Wo   = (const float*)d_in[4];
  const float* relb = (const float*)d_in[5];

  char* ws = (char*)d_ws;
  short* Hb   = (short*)(ws);                        // 8 MB
  short* Wts  = (short*)(ws + ((size_t)8 << 20));    // 4 x 2 MB (WqT WkT WvT WoT)
  short* Qb   = (short*)(ws + ((size_t)16 << 20));   // 8 MB
  short* Kb   = (short*)(ws + ((size_t)24 << 20));   // 8 MB
  short* Vb   = (short*)(ws + ((size_t)32 << 20));   // 8 MB
  short* Vt   = (short*)(ws + ((size_t)40 << 20));   // 8 MB
  short* Ob   = (short*)(ws + ((size_t)48 << 20));   // 8 MB
  float* btab = (float*)(ws + ((size_t)56 << 20));   // 256 KB

  k_cvt_h<<<2048, 256, 0, stream>>>(H, Hb);
  k_wtrans<<<dim3(32, 32, 4), 256, 0, stream>>>(Wq, Wk, Wv, Wo, Wts);
  k_bias<<<256, 256, 0, stream>>>(relb, btab);

  // QKV fused over z: C = Hb * W{q,k,v}^T  (writes Qb, Kb, Vb via cz stride)
  k_gemm_bt<0><<<dim3(8, 32, 3), 256, 0, stream>>>(
      Hb, Wts, Qb, (size_t)1024 * 1024, (size_t)4096 * 1024);

  k_vtrans<<<dim3(32, 32), 256, 0, stream>>>(Vb, Vt);
  k_attn<<<1024, 256, 0, stream>>>(Qb, Kb, Vt, btab, Ob);

  // out = Ob * Wo^T
  k_gemm_bt<1><<<dim3(8, 32, 1), 256, 0, stream>>>(
      Ob, Wts + (size_t)3 * 1024 * 1024, d_out, 0, 0);
}